// Round 7
// baseline (4539.399 us; speedup 1.0000x reference)
//
#include <hip/hip_runtime.h>
#include <math.h>

// GridLSTM one-flag-per-cell dataflow. V=50000, E=300, H=128, L=32, B=8.
// 256 blocks x 256 threads. bid = c*32 + i (i = grid row, c = t-slice chunk).
// Block (i,c) owns state positions t in [c*32, c*32+32): computes the 4 gate
// rows {a*256 + c*32 + s} (so elementwise is block-local), condenses h/c
// inputs itself from RAW published h_o/c_o of the up/left cells (W_ch full in
// registers K-split; W_cc 32 needed rows in registers), publishes raw
// h_o/c_o slice + ONE flag. No mid-cell handoff, no gates in global memory.
// Sync protocol (proven r5/r6): relaxed agent-scope atomics for data;
// producer: data stores -> s_waitcnt vmcnt(0) -> __syncthreads -> relaxed
// flag store. Flags monotonic from ws poison base 0xAAAAAAAA.

// ---------------- workspace layout (float words) ----------------
#define P_OFF     0            // Pproj [32 i][8 b][1024]  (b_ih+b_hh folded)  own-block
#define HYP_OFF   262144       // Hypproj [32 j][8 b][1024]   cross-block (atomic)
#define HO_OFF    524288       // Ho raw [4 dep][32 j][8 b][256]  cross-block
#define CO_OFF    786432       // Co raw [4 dep][32 j][8 b][256]
#define FLAGS_OFF 1048576      // HF [(i*8+c)*32] ; HypF at +8192

#define BASE 0xAAAAAAAAu

__device__ __forceinline__ float sigm(float x) { return 1.f / (1.f + __expf(-x)); }
__device__ __forceinline__ float tanh_fast(float x) { return 1.f - 2.f / (__expf(2.f * x) + 1.f); }

__device__ __forceinline__ unsigned ld_flag(const unsigned* p) {
    return __hip_atomic_load(p, __ATOMIC_RELAXED, __HIP_MEMORY_SCOPE_AGENT);
}
__device__ __forceinline__ void st_flag_relaxed(unsigned* p, unsigned v) {
    __hip_atomic_store(p, v, __ATOMIC_RELAXED, __HIP_MEMORY_SCOPE_AGENT);
}
__device__ __forceinline__ float ld_f32(const float* p) {
    unsigned u = __hip_atomic_load((const unsigned*)p, __ATOMIC_RELAXED, __HIP_MEMORY_SCOPE_AGENT);
    return __uint_as_float(u);
}
__device__ __forceinline__ void st_f32(float* p, float v) {
    __hip_atomic_store((unsigned*)p, __float_as_uint(v), __ATOMIC_RELAXED, __HIP_MEMORY_SCOPE_AGENT);
}
__device__ __forceinline__ float2 ld_f32x2(const float* p) {   // 8B-aligned
    unsigned long long u = __hip_atomic_load((const unsigned long long*)p,
                                             __ATOMIC_RELAXED, __HIP_MEMORY_SCOPE_AGENT);
    float2 r; r.x = __uint_as_float((unsigned)u); r.y = __uint_as_float((unsigned)(u >> 32));
    return r;
}
__device__ __forceinline__ void wait_ge(const unsigned* f, unsigned target) {
    long spins = 0;
    while ((ld_flag(f) - BASE) < target) {
        __builtin_amdgcn_s_sleep(1);
        if (++spins > (1L << 22)) break;   // failsafe: wrong answer > hang
    }
}
__device__ __forceinline__ void drain_vmem() {
    asm volatile("s_waitcnt vmcnt(0)" ::: "memory");
}

__global__ void __launch_bounds__(256, 1) grid_lstm_kernel(
    const int* __restrict__ premise, const int* __restrict__ hypothesis,
    const float* __restrict__ emb,
    const float* __restrict__ W_ih, const float* __restrict__ b_ih,
    const float* __restrict__ W_hh, const float* __restrict__ b_hh,
    const float* __restrict__ W_ch, const float* __restrict__ b_ch,
    const float* __restrict__ W_cc, const float* __restrict__ b_cc,
    const float* __restrict__ W1, const float* __restrict__ b1,
    const float* __restrict__ W2, const float* __restrict__ b2,
    const float* __restrict__ W3, const float* __restrict__ b3,
    float* __restrict__ out, float* __restrict__ ws)
{
    __shared__ float sA[2048];      // ho_up   [8 b][256]
    __shared__ float sB[2048];      // ho_left [8 b][256]
    __shared__ float sC[2048];      // co (up side for c<4, left for c>=4)
    __shared__ float hin[2048];     // condensed [8 b][256] GEMM input
    __shared__ float red[256 * 33]; // reduction scratch / phase0 embs / MLP
    __shared__ float cnbuf[256];    // c_in slice [8 b][32 t]

    const int tid = threadIdx.x;
    const int bid = blockIdx.x;
    const int i   = bid & 31;       // grid row
    const int c   = bid >> 5;       // t-slice chunk 0..7

    float* Pproj   = ws + P_OFF;
    float* Hypproj = ws + HYP_OFF;
    float* Ho      = ws + HO_OFF;
    float* Co      = ws + CO_OFF;
    unsigned* HF   = (unsigned*)(ws + FLAGS_OFF);   // [(i*8+c)*32]
    unsigned* HypF = HF + 8192;                     // [(i*8+c)*32]

    const int tq = tid & 31, ks = tid >> 5;   // K-split thread coords
    const int tl = tid & 31, bb = tid >> 5;   // elementwise thread coords (t_local, b)

    // ================= Phase 0: Pproj[i], Hypproj[i] for this block's gate rows =====
    {
        float* embs = red;   // [2 sides][8][300] = 4800 floats
        for (int idx = tid; idx < 4800; idx += 256) {
            int side = idx / 2400, rem = idx - side * 2400;
            int b = rem / 300, e = rem - b * 300;
            const int* toks = side ? hypothesis : premise;
            embs[idx] = emb[(long)toks[b * 32 + i] * 300 + e];
        }
        __syncthreads();
        #pragma unroll 1
        for (int q = 0; q < 4; q++) {
            const int oo = tid + q * 256;
            const int b = oo >> 7, g = oo & 127;
            const int gr = (g >> 5) * 256 + c * 32 + (g & 31);   // t-sliced gate row
            float accP = b_ih[gr] + b_hh[gr];
            float accH = 0.f;
            const float* wp = W_ih + (long)gr * 600;
            const float* eP = embs + b * 300;
            const float* eH = embs + 2400 + b * 300;
            for (int e = 0; e < 300; e += 4) {
                float4 w1 = *(const float4*)(wp + e);
                float4 w2v = *(const float4*)(wp + 300 + e);
                float4 p4 = *(const float4*)(eP + e);
                float4 h4 = *(const float4*)(eH + e);
                accP += w1.x * p4.x + w1.y * p4.y + w1.z * p4.z + w1.w * p4.w;
                accH += w2v.x * h4.x + w2v.y * h4.y + w2v.z * h4.z + w2v.w * h4.w;
            }
            Pproj[i * 8192 + b * 1024 + gr] = accP;               // own-block only
            st_f32(&Hypproj[i * 8192 + b * 1024 + gr], accH);     // cross-block
        }
    }
    drain_vmem();
    __syncthreads();
    if (tid == 0) st_flag_relaxed(&HypF[(i * 8 + c) * 32], BASE + 1u);

    // ---- register-resident weights (K-split: thread (tq, ks)) ----
    // W_hh: gate rows a*256 + c*32 + tq, K-seg [ks*32, ks*32+32)
    float4 w[4][8], w2[4][8], w3[8];
    #pragma unroll
    for (int a = 0; a < 4; a++) {
        const float* wr = W_hh + (long)(a * 256 + c * 32 + tq) * 256 + ks * 32;
        #pragma unroll
        for (int cc = 0; cc < 8; cc++) w[a][cc] = *(const float4*)(wr + cc * 4);
    }
    // W_ch full: rows tq*4 + a
    #pragma unroll
    for (int a = 0; a < 4; a++) {
        const float* wr = W_ch + (long)(tq * 4 + a) * 256 + ks * 32;
        #pragma unroll
        for (int cc = 0; cc < 8; cc++) w2[a][cc] = *(const float4*)(wr + cc * 4);
    }
    // W_cc: only row (c&3)*32 + tq (the block's c_in slice; one side)
    {
        const float* wr = W_cc + (long)((c & 3) * 32 + tq) * 256 + ks * 32;
        #pragma unroll
        for (int cc = 0; cc < 8; cc++) w3[cc] = *(const float4*)(wr + cc * 4);
    }

    // ================= Wavefront: row i walks j = 0..31 =================
    #pragma unroll 1
    for (int j = 0; j < 32; j++) {
        const bool upok = (i > 0), lfok = (j > 0);
        const bool cok  = (c < 4) ? upok : lfok;

        // ---- dependency waits (parallel spinners), ONE flag class ----
        if (upok && tid < 8)              wait_ge(&HF[((i - 1) * 8 + tid) * 32], (unsigned)(j + 1));
        if (lfok && tid >= 8 && tid < 16) wait_ge(&HF[(i * 8 + (tid - 8)) * 32], (unsigned)j);
        if (tid >= 16 && tid < 24)        wait_ge(&HypF[(j * 8 + (tid - 16)) * 32], 1u);
        __syncthreads();

        // ---- prefetch Pproj/Hypproj for elementwise (thread (tl,bb)) ----
        float hyv[4], ppv[4];
        #pragma unroll
        for (int a = 0; a < 4; a++) {
            const int gr = a * 256 + c * 32 + tl;
            hyv[a] = ld_f32(&Hypproj[j * 8192 + bb * 1024 + gr]);
            ppv[a] = Pproj[i * 8192 + bb * 1024 + gr];
        }

        // ---- stage raw ho_up / ho_left / co (one side) into LDS ----
        const float* HoUp = Ho + ((((i - 1) & 3) * 32 + j) * 2048);
        const float* HoLf = Ho + (((i & 3) * 32 + (j - 1)) * 2048);
        const float* CoS  = (c < 4) ? Co + ((((i - 1) & 3) * 32 + j) * 2048)
                                    : Co + (((i & 3) * 32 + (j - 1)) * 2048);
        #pragma unroll
        for (int r = 0; r < 4; r++) {
            const int idx = r * 256 + tid;   // float2 index in [0,1024)
            float2 u = upok ? ld_f32x2(HoUp + idx * 2) : make_float2(0.f, 0.f);
            float2 l = lfok ? ld_f32x2(HoLf + idx * 2) : make_float2(0.f, 0.f);
            float2 cv = cok ? ld_f32x2(CoS + idx * 2) : make_float2(0.f, 0.f);
            sA[idx * 2] = u.x; sA[idx * 2 + 1] = u.y;
            sB[idx * 2] = l.x; sB[idx * 2 + 1] = l.y;
            sC[idx * 2] = cv.x; sC[idx * 2 + 1] = cv.y;
        }
        __syncthreads();

        // ---- condense partials: h (both sides) and c (one side) ----
        float a2u[4][8], a2l[4][8], a3[8];
        #pragma unroll
        for (int a = 0; a < 4; a++)
            #pragma unroll
            for (int b = 0; b < 8; b++) { a2u[a][b] = 0.f; a2l[a][b] = 0.f; }
        #pragma unroll
        for (int b = 0; b < 8; b++) a3[b] = 0.f;
        #pragma unroll
        for (int cc = 0; cc < 8; cc++) {
            #pragma unroll
            for (int b = 0; b < 8; b++) {
                float4 hu = *(const float4*)(sA + b * 256 + ks * 32 + cc * 4);
                float4 hl = *(const float4*)(sB + b * 256 + ks * 32 + cc * 4);
                float4 cv = *(const float4*)(sC + b * 256 + ks * 32 + cc * 4);
                #pragma unroll
                for (int a = 0; a < 4; a++) {
                    a2u[a][b] += w2[a][cc].x * hu.x + w2[a][cc].y * hu.y
                               + w2[a][cc].z * hu.z + w2[a][cc].w * hu.w;
                    a2l[a][b] += w2[a][cc].x * hl.x + w2[a][cc].y * hl.y
                               + w2[a][cc].z * hl.z + w2[a][cc].w * hl.w;
                }
                a3[b] += w3[cc].x * cv.x + w3[cc].y * cv.y
                       + w3[cc].z * cv.z + w3[cc].w * cv.w;
            }
        }

        // ---- reduce pass: h_n_up -> hin[:,0:128) ----
        #pragma unroll
        for (int a = 0; a < 4; a++)
            #pragma unroll
            for (int b = 0; b < 8; b++) red[tid * 33 + a * 8 + b] = a2u[a][b];
        __syncthreads();
        #pragma unroll
        for (int q = 0; q < 4; q++) {
            const int idx = q * 256 + tid;
            const int t = idx >> 3, b = idx & 7;
            float s = 0.f;
            #pragma unroll
            for (int k = 0; k < 8; k++)
                s += red[(k * 32 + (t >> 2)) * 33 + (t & 3) * 8 + b];
            hin[b * 256 + t] = s + (upok ? b_ch[t] : 0.f);
        }
        __syncthreads();
        // ---- reduce pass: h_n_left -> hin[:,128:256) ----
        #pragma unroll
        for (int a = 0; a < 4; a++)
            #pragma unroll
            for (int b = 0; b < 8; b++) red[tid * 33 + a * 8 + b] = a2l[a][b];
        __syncthreads();
        #pragma unroll
        for (int q = 0; q < 4; q++) {
            const int idx = q * 256 + tid;
            const int t = idx >> 3, b = idx & 7;
            float s = 0.f;
            #pragma unroll
            for (int k = 0; k < 8; k++)
                s += red[(k * 32 + (t >> 2)) * 33 + (t & 3) * 8 + b];
            hin[b * 256 + 128 + t] = s + (lfok ? b_ch[t] : 0.f);
        }
        __syncthreads();
        // ---- reduce pass: c_in slice -> cnbuf ----
        #pragma unroll
        for (int b = 0; b < 8; b++) red[tid * 33 + b] = a3[b];
        __syncthreads();
        float cinv;
        {
            float s = 0.f;
            #pragma unroll
            for (int k = 0; k < 8; k++) s += red[(k * 32 + tl) * 33 + bb];
            cinv = s + (cok ? b_cc[(c & 3) * 32 + tl] : 0.f);
            cnbuf[bb * 32 + tl] = cinv;
        }

        // ---- main gates GEMM from condensed hin (register W_hh) ----
        float acc[4][8];
        #pragma unroll
        for (int a = 0; a < 4; a++)
            #pragma unroll
            for (int b = 0; b < 8; b++) acc[a][b] = 0.f;
        #pragma unroll
        for (int cc = 0; cc < 8; cc++) {
            #pragma unroll
            for (int b = 0; b < 8; b++) {
                float4 h = *(const float4*)(hin + b * 256 + ks * 32 + cc * 4);
                #pragma unroll
                for (int a = 0; a < 4; a++)
                    acc[a][b] += w[a][cc].x * h.x + w[a][cc].y * h.y
                               + w[a][cc].z * h.z + w[a][cc].w * h.w;
            }
        }
        __syncthreads();   // red free (cin pass readers done)
        #pragma unroll
        for (int a = 0; a < 4; a++)
            #pragma unroll
            for (int b = 0; b < 8; b++) red[tid * 33 + a * 8 + b] = acc[a][b];
        __syncthreads();

        // ---- elementwise (local!) + publish raw h_o/c_o slice ----
        {
            float g4[4];
            #pragma unroll
            for (int a = 0; a < 4; a++) {
                float s = 0.f;
                #pragma unroll
                for (int k = 0; k < 8; k++)
                    s += red[(k * 32 + tl) * 33 + a * 8 + bb];
                g4[a] = s + ppv[a] + hyv[a];
            }
            const float ci = cnbuf[bb * 32 + tl];
            const float cnew = sigm(g4[1]) * ci + sigm(g4[0]) * tanh_fast(g4[2]);
            const float hnew = sigm(g4[3]) * tanh_fast(cnew);
            const int base = ((i & 3) * 32 + j) * 2048 + bb * 256 + c * 32 + tl;
            st_f32(&Ho[base], hnew);
            st_f32(&Co[base], cnew);
        }
        drain_vmem();
        __syncthreads();
        if (tid == 0) st_flag_relaxed(&HF[(i * 8 + c) * 32], BASE + (unsigned)(j + 1));
    }

    // ================= Final: condense h_o(31,31) + MLP + softmax (bid 31) ==========
    if (bid == 31) {   // (i=31, c=0): holds full W_ch in w2
        if (tid < 8) wait_ge(&HF[(31 * 8 + tid) * 32], 32u);
        __syncthreads();
        const float* HoF = Ho + (((31 & 3) * 32 + 31) * 2048);
        #pragma unroll
        for (int r = 0; r < 4; r++) {
            const int idx = r * 256 + tid;
            float2 v = ld_f32x2(HoF + idx * 2);
            sA[idx * 2] = v.x; sA[idx * 2 + 1] = v.y;
        }
        __syncthreads();
        float a2u[4][8];
        #pragma unroll
        for (int a = 0; a < 4; a++)
            #pragma unroll
            for (int b = 0; b < 8; b++) a2u[a][b] = 0.f;
        #pragma unroll
        for (int cc = 0; cc < 8; cc++)
            #pragma unroll
            for (int b = 0; b < 8; b++) {
                float4 hu = *(const float4*)(sA + b * 256 + ks * 32 + cc * 4);
                #pragma unroll
                for (int a = 0; a < 4; a++)
                    a2u[a][b] += w2[a][cc].x * hu.x + w2[a][cc].y * hu.y
                               + w2[a][cc].z * hu.z + w2[a][cc].w * hu.w;
            }
        #pragma unroll
        for (int a = 0; a < 4; a++)
            #pragma unroll
            for (int b = 0; b < 8; b++) red[tid * 33 + a * 8 + b] = a2u[a][b];
        __syncthreads();
        #pragma unroll
        for (int q = 0; q < 4; q++) {
            const int idx = q * 256 + tid;
            const int t = idx >> 3, b = idx & 7;
            float s = 0.f;
            #pragma unroll
            for (int k = 0; k < 8; k++)
                s += red[(k * 32 + (t >> 2)) * 33 + (t & 3) * 8 + b];
            hin[b * 256 + t] = s + b_ch[t];
        }
        __syncthreads();
        float* m1 = red;          // [8][128]
        float* m2 = red + 1024;   // [8][128]
        for (int idx = tid; idx < 1024; idx += 256) {
            int b = idx >> 7, o = idx & 127;
            float a = b1[o];
            const float* wr = W1 + o * 128; const float* x = hin + b * 256;
            for (int k = 0; k < 128; k++) a += wr[k] * x[k];
            m1[idx] = fmaxf(a, 0.f);
        }
        __syncthreads();
        for (int idx = tid; idx < 1024; idx += 256) {
            int b = idx >> 7, o = idx & 127;
            float a = b2[o];
            const float* wr = W2 + o * 128; const float* x = m1 + b * 128;
            for (int k = 0; k < 128; k++) a += wr[k] * x[k];
            m2[idx] = fmaxf(a, 0.f);
        }
        __syncthreads();
        if (tid < 8) {
            const int b = tid;
            float lg[3];
            for (int cc = 0; cc < 3; cc++) {
                float a = b3[cc];
                const float* wr = W3 + cc * 128; const float* x = m2 + b * 128;
                for (int k = 0; k < 128; k++) a += wr[k] * x[k];
                lg[cc] = a;
            }
            float m = fmaxf(lg[0], fmaxf(lg[1], lg[2]));
            float e0 = expf(lg[0] - m), e1 = expf(lg[1] - m), e2 = expf(lg[2] - m);
            float s = e0 + e1 + e2;
            out[b * 3 + 0] = e0 / s;
            out[b * 3 + 1] = e1 / s;
            out[b * 3 + 2] = e2 / s;
        }
    }
}

extern "C" void kernel_launch(void* const* d_in, const int* in_sizes, int n_in,
                              void* d_out, int out_size, void* d_ws, size_t ws_size,
                              hipStream_t stream) {
    const int*   premise    = (const int*)d_in[0];
    const int*   hypothesis = (const int*)d_in[1];
    const float* emb        = (const float*)d_in[2];
    const float* W_ih       = (const float*)d_in[3];
    const float* b_ih       = (const float*)d_in[4];
    const float* W_hh       = (const float*)d_in[5];
    const float* b_hh       = (const float*)d_in[6];
    const float* W_ch       = (const float*)d_in[7];
    const float* b_ch       = (const float*)d_in[8];
    const float* W_cc       = (const float*)d_in[9];
    const float* b_cc       = (const float*)d_in[10];
    const float* W1         = (const float*)d_in[11];
    const float* b1         = (const float*)d_in[12];
    const float* W2         = (const float*)d_in[13];
    const float* b2         = (const float*)d_in[14];
    const float* W3         = (const float*)d_in[15];
    const float* b3         = (const float*)d_in[16];
    float* out = (float*)d_out;
    float* ws  = (float*)d_ws;

    (void)in_sizes; (void)n_in; (void)out_size; (void)ws_size;

    grid_lstm_kernel<<<dim3(256), dim3(256), 0, stream>>>(
        premise, hypothesis, emb, W_ih, b_ih, W_hh, b_hh,
        W_ch, b_ch, W_cc, b_cc, W1, b1, W2, b2, W3, b3, out, ws);
}

// Round 9
// 815.874 us; speedup vs baseline: 5.5638x; 5.5638x over previous
//
#include <hip/hip_runtime.h>
#include <math.h>

// GridLSTM one-flag-per-cell dataflow, fused f16 weights. V=50000,E=300,H=128,L=32,B=8.
// 256 blocks x 256 threads. bid = c*32 + i (i = grid row, c = t-slice chunk 0..7).
// Key identity: h_in = [W_ch@ho_up + b_ch ; W_ch@ho_left + b_ch]  =>
//   gates = WU@ho_up + WL@ho_left + (Pproj+b) + Hypproj + upok*bU + lfok*bL
// with WU = W_hh[:,:128]@W_ch, WL = W_hh[:,128:]@W_ch (precomputed on device,
// packed f16x2, consumed via v_dot2_f32_f16 -> 128 VGPRs of weights/thread).
// c_in slice: W_cc rows [ (c&3)*32 .. +32 ) @ co_side (fp32, 32 VGPRs).
// Elementwise is block-local (t-sliced gate ownership); ONE flag per cell.
// Sync protocol (proven r5-r7): relaxed agent-scope atomics for data; producer:
// data stores -> s_waitcnt vmcnt(0) -> __syncthreads -> relaxed flag store.
// Flags monotonic from ws poison base 0xAAAAAAAA.

typedef _Float16 h2 __attribute__((ext_vector_type(2)));

__device__ __forceinline__ h2 pk_f16(float a, float b) {
    return __builtin_bit_cast(h2, __builtin_amdgcn_cvt_pkrtz(a, b));
}

// ---------------- workspace layout (float words) ----------------
#define HYP_OFF   0            // Hypproj [32 j][8 b][1024]          (atomic)
#define HO_OFF    262144       // Ho raw [4 dep][32 j][8 b][256]     (atomic)
#define CO_OFF    524288       // Co raw [4 dep][32 j][8 b][256]     (atomic)
#define WP_OFF    786432       // fused wts packed h2 [1024 g][256]  (atomic, uint)
#define B_OFF     1048576      // bU[1024] | bL[1024]
#define FLAGS_OFF 1050624      // HF [(i*8+c)*16] (4096) | InitF [p*16] (4096)

#define BASE 0xAAAAAAAAu

__device__ __forceinline__ float sigm(float x) { return 1.f / (1.f + __expf(-x)); }
__device__ __forceinline__ float tanh_fast(float x) { return 1.f - 2.f / (__expf(2.f * x) + 1.f); }

__device__ __forceinline__ unsigned ld_flag(const unsigned* p) {
    return __hip_atomic_load(p, __ATOMIC_RELAXED, __HIP_MEMORY_SCOPE_AGENT);
}
__device__ __forceinline__ void st_flag(unsigned* p, unsigned v) {
    __hip_atomic_store(p, v, __ATOMIC_RELAXED, __HIP_MEMORY_SCOPE_AGENT);
}
__device__ __forceinline__ float ld_f32(const float* p) {
    unsigned u = __hip_atomic_load((const unsigned*)p, __ATOMIC_RELAXED, __HIP_MEMORY_SCOPE_AGENT);
    return __uint_as_float(u);
}
__device__ __forceinline__ void st_f32(float* p, float v) {
    __hip_atomic_store((unsigned*)p, __float_as_uint(v), __ATOMIC_RELAXED, __HIP_MEMORY_SCOPE_AGENT);
}
__device__ __forceinline__ void st_u32(unsigned* p, unsigned v) {
    __hip_atomic_store(p, v, __ATOMIC_RELAXED, __HIP_MEMORY_SCOPE_AGENT);
}
__device__ __forceinline__ float2 ld_f32x2(const float* p) {   // 8B-aligned
    unsigned long long u = __hip_atomic_load((const unsigned long long*)p,
                                             __ATOMIC_RELAXED, __HIP_MEMORY_SCOPE_AGENT);
    float2 r; r.x = __uint_as_float((unsigned)u); r.y = __uint_as_float((unsigned)(u >> 32));
    return r;
}
__device__ __forceinline__ void ld_u32x2(const unsigned* p, unsigned& a, unsigned& b) {
    unsigned long long u = __hip_atomic_load((const unsigned long long*)p,
                                             __ATOMIC_RELAXED, __HIP_MEMORY_SCOPE_AGENT);
    a = (unsigned)u; b = (unsigned)(u >> 32);
}
__device__ __forceinline__ void wait_ge(const unsigned* f, unsigned target) {
    long spins = 0;
    while ((ld_flag(f) - BASE) < target) {
        __builtin_amdgcn_s_sleep(1);
        if (++spins > (1L << 22)) break;   // failsafe: wrong answer > hang
    }
}
__device__ __forceinline__ void drain_vmem() {
    asm volatile("s_waitcnt vmcnt(0)" ::: "memory");
}

__global__ void __launch_bounds__(256, 1) grid_lstm_kernel(
    const int* __restrict__ premise, const int* __restrict__ hypothesis,
    const float* __restrict__ emb,
    const float* __restrict__ W_ih, const float* __restrict__ b_ih,
    const float* __restrict__ W_hh, const float* __restrict__ b_hh,
    const float* __restrict__ W_ch, const float* __restrict__ b_ch,
    const float* __restrict__ W_cc, const float* __restrict__ b_cc,
    const float* __restrict__ W1, const float* __restrict__ b1,
    const float* __restrict__ W2, const float* __restrict__ b2,
    const float* __restrict__ W3, const float* __restrict__ b3,
    float* __restrict__ out, float* __restrict__ ws)
{
    __shared__ h2    hAB[2048];      // f16 [8 b][256 kk]: kk<128 up, kk>=128 left (8KB)
    __shared__ float sCo[2048];      // f32 co_side [8 b][256] (8KB)
    __shared__ float ppL[1024];      // Pproj slice [8 b][128 g], g=(a<<5)|s (4KB)
    __shared__ float red[8448];      // gate partials [256][33] / embs / MLP (33.8KB)
    __shared__ float red2[2304];     // c partials [256][9] (9.2KB)

    const int tid = threadIdx.x;
    const int bid = blockIdx.x;
    const int i   = bid & 31;       // grid row
    const int c   = bid >> 5;       // t-slice chunk

    float*    Hypproj = ws + HYP_OFF;
    float*    Ho      = ws + HO_OFF;
    float*    Co      = ws + CO_OFF;
    unsigned* WP      = (unsigned*)(ws + WP_OFF);
    float*    BU      = ws + B_OFF;
    float*    BL      = ws + B_OFF + 1024;
    unsigned* HF      = (unsigned*)(ws + FLAGS_OFF);          // [(i*8+c)*16]
    unsigned* InitF   = (unsigned*)(ws + FLAGS_OFF) + 4096;   // [p*16]

    const int tq = tid & 31, ks = tid >> 5;   // GEMM K-split coords
    const int tl = tid & 31, bb = tid >> 5;   // elementwise coords (t_local, batch)

    // ================= Init A: Pproj (LDS) + Hypproj for this block's gate rows ====
    {
        float* embs = red;   // [2 sides][8][300] = 4800 floats
        for (int idx = tid; idx < 4800; idx += 256) {
            int side = idx / 2400, rem = idx - side * 2400;
            int b = rem / 300, e = rem - b * 300;
            const int* toks = side ? hypothesis : premise;
            embs[idx] = emb[(long)toks[b * 32 + i] * 300 + e];
        }
        __syncthreads();
        #pragma unroll 1
        for (int q = 0; q < 4; q++) {
            const int oo = tid + q * 256;
            const int b = oo >> 7, g = oo & 127;
            const int gr = (g >> 5) * 256 + c * 32 + (g & 31);   // t-sliced gate row
            float accP = b_ih[gr] + b_hh[gr];
            float accH = 0.f;
            const float* wp = W_ih + (long)gr * 600;
            const float* eP = embs + b * 300;
            const float* eH = embs + 2400 + b * 300;
            for (int e = 0; e < 300; e += 4) {
                float4 w1 = *(const float4*)(wp + e);
                float4 w2v = *(const float4*)(wp + 300 + e);
                float4 p4 = *(const float4*)(eP + e);
                float4 h4 = *(const float4*)(eH + e);
                accP += w1.x * p4.x + w1.y * p4.y + w1.z * p4.z + w1.w * p4.w;
                accH += w2v.x * h4.x + w2v.y * h4.y + w2v.z * h4.z + w2v.w * h4.w;
            }
            st_f32(&Hypproj[i * 8192 + b * 1024 + gr], accH);     // cross-block
            ppL[b * 128 + g] = accP;                              // block-local
        }
        __syncthreads();   // embs (red) free
    }

    // ================= Init B: fused weight rows [4*bid, 4*bid+4) =================
    {
        const int tr = tid >> 6, col = (tid & 63) * 4;
        const int r  = bid * 4 + tr;
        float u[4] = {0.f, 0.f, 0.f, 0.f}, l[4] = {0.f, 0.f, 0.f, 0.f};
        const float* whU = W_hh + (long)r * 256;
        const float* whL = whU + 128;
        for (int k = 0; k < 128; k++) {
            const float wu = whU[k], wl = whL[k];
            float4 wc = *(const float4*)(W_ch + (long)k * 256 + col);
            u[0] += wu * wc.x; u[1] += wu * wc.y; u[2] += wu * wc.z; u[3] += wu * wc.w;
            l[0] += wl * wc.x; l[1] += wl * wc.y; l[2] += wl * wc.z; l[3] += wl * wc.w;
        }
        unsigned* wrow = WP + (long)r * 256;
        st_u32(&wrow[col / 2],       __builtin_bit_cast(unsigned, __builtin_amdgcn_cvt_pkrtz(u[0], u[1])));
        st_u32(&wrow[col / 2 + 1],   __builtin_bit_cast(unsigned, __builtin_amdgcn_cvt_pkrtz(u[2], u[3])));
        st_u32(&wrow[128 + col / 2],     __builtin_bit_cast(unsigned, __builtin_amdgcn_cvt_pkrtz(l[0], l[1])));
        st_u32(&wrow[128 + col / 2 + 1], __builtin_bit_cast(unsigned, __builtin_amdgcn_cvt_pkrtz(l[2], l[3])));
        if ((tid & 63) == 0) {   // bias projections for this row
            float su = 0.f, sl = 0.f;
            for (int k = 0; k < 128; k++) { su += whU[k] * b_ch[k]; sl += whL[k] * b_ch[k]; }
            st_f32(&BU[r], su); st_f32(&BL[r], sl);
        }
    }
    drain_vmem();
    __syncthreads();
    if (tid == 0) st_flag(&InitF[bid * 16], BASE + 1u);

    // ---- wait ALL inits (covers every Hypproj row + all fused weights) ----
    wait_ge(&InitF[tid * 16], 1u);
    __syncthreads();

    // ---- load fused weight slice -> registers (f16x2), W_cc slice (fp32) ----
    h2 w[4][32];                  // 128 VGPRs
    #pragma unroll
    for (int a = 0; a < 4; a++) {
        const unsigned* src = WP + (long)(a * 256 + c * 32 + tq) * 256 + ks * 32;
        #pragma unroll
        for (int m = 0; m < 16; m++) {
            unsigned lo, hi;
            ld_u32x2(src + m * 2, lo, hi);
            w[a][2 * m]     = __builtin_bit_cast(h2, lo);
            w[a][2 * m + 1] = __builtin_bit_cast(h2, hi);
        }
    }
    float4 w3[8];                 // 32 VGPRs: W_cc row (c&3)*32+tq, K-seg ks*32..+32
    {
        const float* wr = W_cc + (long)((c & 3) * 32 + tq) * 256 + ks * 32;
        #pragma unroll
        for (int m = 0; m < 8; m++) w3[m] = *(const float4*)(wr + m * 4);
    }
    float bUv[4], bLv[4];
    #pragma unroll
    for (int a = 0; a < 4; a++) {
        bUv[a] = ld_f32(&BU[a * 256 + c * 32 + tl]);
        bLv[a] = ld_f32(&BL[a * 256 + c * 32 + tl]);
    }

    // ================= Wavefront: row i walks j = 0..31 =================
    #pragma unroll 1
    for (int j = 0; j < 32; j++) {
        const bool upok = (i > 0), lfok = (j > 0);
        const bool cok  = (c < 4) ? upok : lfok;
        const int  jl   = lfok ? (j - 1) : 0;

        // ---- dependency waits (parallel spinners) ----
        if (upok && tid < 8)              wait_ge(&HF[((i - 1) * 8 + tid) * 16], (unsigned)(j + 1));
        if (lfok && tid >= 8 && tid < 16) wait_ge(&HF[(i * 8 + (tid - 8)) * 16], (unsigned)j);
        __syncthreads();

        // ---- prefetch Hypproj for elementwise ----
        float hyv[4];
        #pragma unroll
        for (int a = 0; a < 4; a++)
            hyv[a] = ld_f32(&Hypproj[j * 8192 + bb * 1024 + a * 256 + c * 32 + tl]);

        // ---- stage raw ho_up / ho_left (f16) and co_side (f32) ----
        const float* HoUp = Ho + ((((i - 1) & 3) * 32 + j) * 2048);
        const float* HoLf = Ho + (((i & 3) * 32 + jl) * 2048);
        const float* CoS  = (c < 4) ? Co + ((((i - 1) & 3) * 32 + j) * 2048)
                                    : Co + (((i & 3) * 32 + jl) * 2048);
        #pragma unroll
        for (int r = 0; r < 4; r++) {
            const int idx = r * 256 + tid;           // 0..1023
            const int b = idx >> 7, kk = idx & 127;  // f32 pair (2kk, 2kk+1)
            float2 u = upok ? ld_f32x2(HoUp + b * 256 + 2 * kk) : make_float2(0.f, 0.f);
            float2 l = lfok ? ld_f32x2(HoLf + b * 256 + 2 * kk) : make_float2(0.f, 0.f);
            float2 cv = cok ? ld_f32x2(CoS + b * 256 + 2 * kk) : make_float2(0.f, 0.f);
            hAB[b * 256 + kk]       = pk_f16(u.x, u.y);
            hAB[b * 256 + 128 + kk] = pk_f16(l.x, l.y);
            sCo[b * 256 + 2 * kk] = cv.x; sCo[b * 256 + 2 * kk + 1] = cv.y;
        }
        __syncthreads();

        // ---- fused gates GEMM (f16 dot2) + c-path (fp32) ----
        float acc[4][8], a3[8];
        #pragma unroll
        for (int a = 0; a < 4; a++)
            #pragma unroll
            for (int b = 0; b < 8; b++) acc[a][b] = 0.f;
        #pragma unroll
        for (int b = 0; b < 8; b++) a3[b] = 0.f;
        #pragma unroll
        for (int b = 0; b < 8; b++) {
            const h2*    hb = hAB + b * 256 + ks * 32;
            const float* cb = sCo + b * 256 + ks * 32;
            #pragma unroll
            for (int m4 = 0; m4 < 8; m4++) {
                uint4 hu = *(const uint4*)(hb + m4 * 4);
                h2 h0 = __builtin_bit_cast(h2, hu.x);
                h2 h1 = __builtin_bit_cast(h2, hu.y);
                h2 h2v = __builtin_bit_cast(h2, hu.z);
                h2 h3 = __builtin_bit_cast(h2, hu.w);
                #pragma unroll
                for (int a = 0; a < 4; a++) {
                    acc[a][b] = __builtin_amdgcn_fdot2(w[a][m4 * 4],     h0,  acc[a][b], false);
                    acc[a][b] = __builtin_amdgcn_fdot2(w[a][m4 * 4 + 1], h1,  acc[a][b], false);
                    acc[a][b] = __builtin_amdgcn_fdot2(w[a][m4 * 4 + 2], h2v, acc[a][b], false);
                    acc[a][b] = __builtin_amdgcn_fdot2(w[a][m4 * 4 + 3], h3,  acc[a][b], false);
                }
                float4 cv = *(const float4*)(cb + m4 * 4);
                a3[b] += w3[m4].x * cv.x + w3[m4].y * cv.y + w3[m4].z * cv.z + w3[m4].w * cv.w;
            }
        }
        #pragma unroll
        for (int a = 0; a < 4; a++)
            #pragma unroll
            for (int b = 0; b < 8; b++) red[tid * 33 + a * 8 + b] = acc[a][b];
        #pragma unroll
        for (int b = 0; b < 8; b++) red2[tid * 9 + b] = a3[b];
        __syncthreads();

        // ---- elementwise (block-local) + publish raw h_o/c_o slice ----
        {
            float g4[4];
            #pragma unroll
            for (int a = 0; a < 4; a++) {
                float s = 0.f;
                #pragma unroll
                for (int k = 0; k < 8; k++)
                    s += red[(k * 32 + tl) * 33 + a * 8 + bb];
                s += ppL[bb * 128 + a * 32 + tl] + hyv[a];
                if (upok) s += bUv[a];
                if (lfok) s += bLv[a];
                g4[a] = s;
            }
            float ci = 0.f;
            #pragma unroll
            for (int k = 0; k < 8; k++) ci += red2[(k * 32 + tl) * 9 + bb];
            if (cok) ci += b_cc[(c & 3) * 32 + tl];
            const float cnew = sigm(g4[1]) * ci + sigm(g4[0]) * tanh_fast(g4[2]);
            const float hnew = sigm(g4[3]) * tanh_fast(cnew);
            const int base = ((i & 3) * 32 + j) * 2048 + bb * 256 + c * 32 + tl;
            st_f32(&Ho[base], hnew);
            st_f32(&Co[base], cnew);
        }
        drain_vmem();
        __syncthreads();
        if (tid == 0) st_flag(&HF[(i * 8 + c) * 16], BASE + (unsigned)(j + 1));
    }

    // ================= Final: condense ho(31,31) + MLP + softmax (bid 31) ==========
    if (bid == 31) {
        if (tid < 8) wait_ge(&HF[(31 * 8 + tid) * 16], 32u);
        __syncthreads();
        const float* HoF = Ho + (((31 & 3) * 32 + 31) * 2048);
        #pragma unroll
        for (int r = 0; r < 4; r++) {
            const int idx = r * 256 + tid;
            float2 v = ld_f32x2(HoF + idx * 2);
            sCo[idx * 2] = v.x; sCo[idx * 2 + 1] = v.y;
        }
        __syncthreads();
        // condense: hcond[b][o] = b_ch[o] + W_ch[o,:] @ ho[b,:]
        #pragma unroll 1
        for (int q = 0; q < 4; q++) {
            const int oo = tid + q * 256;
            const int b = oo >> 7, o = oo & 127;
            float a = b_ch[o];
            const float* wr = W_ch + (long)o * 256;
            const float* x = sCo + b * 256;
            for (int k = 0; k < 256; k += 4) {
                float4 wv = *(const float4*)(wr + k);
                float4 xv = *(const float4*)(x + k);
                a += wv.x * xv.x + wv.y * xv.y + wv.z * xv.z + wv.w * xv.w;
            }
            ppL[b * 128 + o] = a;
        }
        __syncthreads();
        float* m1 = red;          // [8][128]
        float* m2 = red + 1024;   // [8][128]
        for (int idx = tid; idx < 1024; idx += 256) {
            int b = idx >> 7, o = idx & 127;
            float a = b1[o];
            const float* wr = W1 + o * 128; const float* x = ppL + b * 128;
            for (int k = 0; k < 128; k++) a += wr[k] * x[k];
            m1[idx] = fmaxf(a, 0.f);
        }
        __syncthreads();
        for (int idx = tid; idx < 1024; idx += 256) {
            int b = idx >> 7, o = idx & 127;
            float a = b2[o];
            const float* wr = W2 + o * 128; const float* x = m1 + b * 128;
            for (int k = 0; k < 128; k++) a += wr[k] * x[k];
            m2[idx] = fmaxf(a, 0.f);
        }
        __syncthreads();
        if (tid < 8) {
            const int b = tid;
            float lg[3];
            for (int cc = 0; cc < 3; cc++) {
                float a = b3[cc];
                const float* wr = W3 + cc * 128; const float* x = m2 + b * 128;
                for (int k = 0; k < 128; k++) a += wr[k] * x[k];
                lg[cc] = a;
            }
            float m = fmaxf(lg[0], fmaxf(lg[1], lg[2]));
            float e0 = expf(lg[0] - m), e1 = expf(lg[1] - m), e2 = expf(lg[2] - m);
            float s = e0 + e1 + e2;
            out[b * 3 + 0] = e0 / s;
            out[b * 3 + 1] = e1 / s;
            out[b * 3 + 2] = e2 / s;
        }
    }
}

extern "C" void kernel_launch(void* const* d_in, const int* in_sizes, int n_in,
                              void* d_out, int out_size, void* d_ws, size_t ws_size,
                              hipStream_t stream) {
    const int*   premise    = (const int*)d_in[0];
    const int*   hypothesis = (const int*)d_in[1];
    const float* emb        = (const float*)d_in[2];
    const float* W_ih       = (const float*)d_in[3];
    const float* b_ih       = (const float*)d_in[4];
    const float* W_hh       = (const float*)d_in[5];
    const float* b_hh       = (const float*)d_in[6];
    const float* W_ch       = (const float*)d_in[7];
    const float* b_ch       = (const float*)d_in[8];
    const float* W_cc       = (const float*)d_in[9];
    const float* b_cc       = (const float*)d_in[10];
    const float* W1         = (const float*)d_in[11];
    const float* b1         = (const float*)d_in[12];
    const float* W2         = (const float*)d_in[13];
    const float* b2         = (const float*)d_in[14];
    const float* W3         = (const float*)d_in[15];
    const float* b3         = (const float*)d_in[16];
    float* out = (float*)d_out;
    float* ws  = (float*)d_ws;

    (void)in_sizes; (void)n_in; (void)out_size; (void)ws_size;

    grid_lstm_kernel<<<dim3(256), dim3(256), 0, stream>>>(
        premise, hypothesis, emb, W_ih, b_ih, W_hh, b_hh,
        W_ch, b_ch, W_cc, b_cc, W1, b1, W2, b2, W3, b3, out, ws);
}